// Round 8
// baseline (21038.643 us; speedup 1.0000x reference)
//
#include <hip/hip_runtime.h>

#define T_STEPS 365
#define BATCH   2048
#define INP     9
#define HID     50
#define MB      16              // batch per pair (MFMA col dim)
#define NPAIR   (BATCH/MB)      // 128 producer/consumer CU pairs
#define NT      1024            // 16 waves
#define NWC     13              // compute waves (13 tiles of 16 gate rows)
#define RING    8               // h0 handoff ring depth
#define SLOTDW  (MB*32)         // 512 dwords per h0 slot ([m][u-pair] packed)
#define WS_DW   (NPAIR*64 + NPAIR*RING*SLOTDW)
#define L2E     1.4426950408889634f

typedef __attribute__((ext_vector_type(8))) short short8;
typedef __attribute__((ext_vector_type(4))) float float4v;
typedef __attribute__((ext_vector_type(4))) unsigned int uint4v;

__device__ __forceinline__ unsigned f2bf(float v) {
    unsigned u = __builtin_bit_cast(unsigned, v);
    return (u + 0x7FFFu + ((u >> 16) & 1u)) >> 16;
}

// lgkm-only phase barrier: LDS drains, global ops stay in flight.
#define PHASE_BARRIER() do {                                  \
    asm volatile("s_waitcnt lgkmcnt(0)" ::: "memory");        \
    __builtin_amdgcn_s_barrier();                             \
    __builtin_amdgcn_sched_barrier(0);                        \
} while (0)

// [16][64] bf16 LDS tile, XOR-swizzled for low-conflict b128 reads.
__device__ __forceinline__ int offA(int m, int k) {   // ushort units
    return (m * 64 + k) ^ ((m & 7) << 3);
}

// Producer/consumer CU-pair LSTM: block p (role A) runs layer0 for batch
// group p; block p+128 (role B) runs layer1+FC one step behind, consuming
// h0 through a ring of RING global slots with acquire/release counters.
__global__ __launch_bounds__(NT, 4)
void lstm_ab(const float* __restrict__ x,
             const float* __restrict__ w_ih0, const float* __restrict__ w_hh0,
             const float* __restrict__ b_ih0, const float* __restrict__ b_hh0,
             const float* __restrict__ w_ih1, const float* __restrict__ w_hh1,
             const float* __restrict__ b_ih1, const float* __restrict__ b_hh1,
             const float* __restrict__ fc_w, const float* __restrict__ fc_b,
             float* __restrict__ out, unsigned* __restrict__ ws)
{
    __shared__ __align__(16) unsigned short HS[2][MB * 64];  // A: h0|x ; B: h1
    __shared__ float FCP[2][NWC][MB];

    const int tid  = threadIdx.x;
    const int w    = tid >> 6;
    const int lid  = tid & 63;
    const int mcol = lid & 15;
    const int kgrp = lid >> 4;
    const int kb8  = kgrp * 8;
    const bool roleB = (blockIdx.x >= NPAIR);
    const int pair = blockIdx.x & (NPAIR - 1);
    const int b0   = pair * MB;
    const float fcb = fc_b[0];

    unsigned* actr = ws + pair * 64;         // producer progress (13/step)
    unsigned* bctr = actr + 32;              // consumer progress (13/step)
    unsigned* h0g  = ws + NPAIR * 64 + pair * (RING * SLOTDW);

    // ---- per-wave tile weights: wave w<13 owns tile T=w ----
    // gate-interleaved rows: tile row r = 4*unit + gate -> original row = gate*50 + unit
    const int T = (w < NWC) ? w : 0;
    const int r = T * 16 + mcol;
    const bool rv = (r < 4 * HID);
    const int u_r = r >> 2, g_r = r & 3;
    const int orig = g_r * HID + u_r;
    const float rsc = (g_r == 2) ? (-2.f * L2E) : (-L2E);   // exp2 prescale
    const int u = T * 4 + kgrp;              // unit this lane's D-regs cover

    // wk[0..1]: matrix-1 halves (A: w_hh0+w_ih0 on [h0|x]; B: w_ih1 on h0)
    // wk[2..3]: matrix-2 halves (B only: w_hh1 on h1)
    short8 wk[4];
    #pragma unroll
    for (int q = 0; q < 4; ++q) {
        short8 f;
        #pragma unroll
        for (int j = 0; j < 8; ++j) {
            const int k = (q & 1) * 32 + kb8 + j;
            float val = 0.f;
            if (rv) {
                if (roleB) {
                    if (k < HID) val = (q < 2) ? w_ih1[orig * HID + k]
                                               : w_hh1[orig * HID + k];
                } else if (q < 2) {
                    if (k < HID)            val = w_hh0[orig * HID + k];
                    else if (k < HID + INP) val = w_ih0[orig * INP + (k - HID)];
                }
            }
            f[j] = (short)f2bf(val * rsc);
        }
        wk[q] = f;
    }
    float bs[4];
    #pragma unroll
    for (int rr = 0; rr < 4; ++rr) {
        const int row = T * 16 + kgrp * 4 + rr;   // = 4*u + rr
        const bool bv = (row < 4 * HID) && (w < NWC);
        const float bsc = (rr == 2) ? (-2.f * L2E) : (-L2E);
        bs[rr] = 0.f;
        if (bv) bs[rr] = roleB ? (b_ih1[rr * HID + u] + b_hh1[rr * HID + u]) * bsc
                               : (b_ih0[rr * HID + u] + b_hh0[rr * HID + u]) * bsc;
    }
    const float fcwv = (roleB && w < NWC && u < HID) ? fc_w[u] : 0.f;

    // ---- x loader identity (role A waves 13..15; 144 values) ----
    const int xi = (w - NWC) * 64 + lid;
    const bool xact = (!roleB) && (w >= NWC) && (xi < MB * INP);
    const int xm = xact ? xi / INP : 0;
    const int xj = xact ? xi - xm * INP : 0;

    // ---- LDS init ----
    for (int i = tid; i < 2 * MB * 64; i += NT) (&HS[0][0])[i] = 0;
    for (int i = tid; i < 2 * NWC * MB; i += NT) (&FCP[0][0][0])[i] = 0.f;
    __syncthreads();
    float xreg = 0.f;
    if (xact) {   // x(0) into buf1 (phase 0 reads cur=1); xreg <- x(1)
        HS[1][offA(xm, HID + xj)] = (unsigned short)f2bf(x[(size_t)(b0 + xm) * INP + xj]);
        xreg = x[((size_t)BATCH + b0 + xm) * INP + xj];
    }
    __syncthreads();

    float cst = 0.f;

    if (!roleB) {
        // =================== role A: layer 0 producer ===================
        for (int ph = 0; ph < T_STEPS; ++ph) {
            const int cur = (ph + 1) & 1, nxt = ph & 1;
            if (w < NWC) {
                if (ph >= RING && lid == 0) {       // ring credit: B consumed slot ph-8
                    const unsigned tgt = (unsigned)(NWC * (ph - RING + 1));
                    while (__hip_atomic_load(bctr, __ATOMIC_ACQUIRE, __HIP_MEMORY_SCOPE_AGENT) < tgt)
                        __builtin_amdgcn_s_sleep(2);
                }
                asm volatile("" ::: "memory");
                const short8 f0 = *(const short8*)&HS[cur][offA(mcol, kb8)];
                const short8 f1 = *(const short8*)&HS[cur][offA(mcol, 32 + kb8)];
                float4v acc = {bs[0], bs[1], bs[2], bs[3]};
                acc = __builtin_amdgcn_mfma_f32_16x16x32_bf16(wk[0], f0, acc, 0, 0, 0);
                acc = __builtin_amdgcn_mfma_f32_16x16x32_bf16(wk[1], f1, acc, 0, 0, 0);
                const float gi = __builtin_amdgcn_rcpf(1.f + __builtin_amdgcn_exp2f(acc[0]));
                const float gf = __builtin_amdgcn_rcpf(1.f + __builtin_amdgcn_exp2f(acc[1]));
                const float g2 = __builtin_amdgcn_rcpf(1.f + __builtin_amdgcn_exp2f(acc[2]));
                const float go = __builtin_amdgcn_rcpf(1.f + __builtin_amdgcn_exp2f(acc[3]));
                const float gg = __builtin_fmaf(2.f, g2, -1.f);
                cst = gf * cst + gi * gg;
                const float Ec = __builtin_amdgcn_exp2f(cst * (-2.f * L2E));
                const float tc = __builtin_fmaf(2.f, __builtin_amdgcn_rcpf(1.f + Ec), -1.f);
                const float h0v = go * tc;
                const unsigned hsu = f2bf(h0v);
                const unsigned prt = (unsigned)__shfl_xor((int)hsu, 16);  // partner u+1
                if (u < HID) HS[nxt][offA(mcol, u)] = (unsigned short)hsu;
                if (!(kgrp & 1) && (u + 1) < HID)    // pack (h[u],h[u+1]) -> dword [m][u/2]
                    h0g[(ph & (RING - 1)) * SLOTDW + mcol * 32 + (u >> 1)] = (prt << 16) | hsu;
                if (lid == 0)                        // publish: orders the slot stores
                    __hip_atomic_fetch_add(actr, 1u, __ATOMIC_RELEASE, __HIP_MEMORY_SCOPE_AGENT);
            } else if (xact) {
                if (ph + 1 < T_STEPS) HS[nxt][offA(xm, HID + xj)] = (unsigned short)f2bf(xreg);
                if (ph + 2 < T_STEPS) xreg = x[((size_t)(ph + 2) * BATCH + b0 + xm) * INP + xj];
            }
            PHASE_BARRIER();
        }
    } else {
        // =================== role B: layer 1 + FC consumer ===================
        for (int tb = 0; tb < T_STEPS; ++tb) {
            const int cur = (tb + 1) & 1, nxt = tb & 1;
            if (w < NWC) {
                if (lid == 0) {                      // wait for h0(tb) published
                    const unsigned tgt = (unsigned)(NWC * (tb + 1));
                    while (__hip_atomic_load(actr, __ATOMIC_ACQUIRE, __HIP_MEMORY_SCOPE_AGENT) < tgt)
                        __builtin_amdgcn_s_sleep(2);
                }
                asm volatile("" ::: "memory");
                const unsigned* slot = h0g + (tb & (RING - 1)) * SLOTDW + mcol * 32;
                const uint4v g0 = *(const uint4v*)(slot + kgrp * 4);        // u = kb8..kb8+7
                const uint4v g1 = *(const uint4v*)(slot + 16 + kgrp * 4);   // u = 32+kb8..
                const short8 f2 = *(const short8*)&HS[cur][offA(mcol, kb8)];
                const short8 f3 = *(const short8*)&HS[cur][offA(mcol, 32 + kb8)];
                float4v accA = {bs[0], bs[1], bs[2], bs[3]};
                float4v accB = {0.f, 0.f, 0.f, 0.f};
                accA = __builtin_amdgcn_mfma_f32_16x16x32_bf16(wk[0], __builtin_bit_cast(short8, g0), accA, 0, 0, 0);
                accB = __builtin_amdgcn_mfma_f32_16x16x32_bf16(wk[2], f2, accB, 0, 0, 0);
                accA = __builtin_amdgcn_mfma_f32_16x16x32_bf16(wk[1], __builtin_bit_cast(short8, g1), accA, 0, 0, 0);
                accB = __builtin_amdgcn_mfma_f32_16x16x32_bf16(wk[3], f3, accB, 0, 0, 0);
                const float gi = __builtin_amdgcn_rcpf(1.f + __builtin_amdgcn_exp2f(accA[0] + accB[0]));
                const float gf = __builtin_amdgcn_rcpf(1.f + __builtin_amdgcn_exp2f(accA[1] + accB[1]));
                const float g2 = __builtin_amdgcn_rcpf(1.f + __builtin_amdgcn_exp2f(accA[2] + accB[2]));
                const float go = __builtin_amdgcn_rcpf(1.f + __builtin_amdgcn_exp2f(accA[3] + accB[3]));
                const float gg = __builtin_fmaf(2.f, g2, -1.f);
                cst = gf * cst + gi * gg;
                const float Ec = __builtin_amdgcn_exp2f(cst * (-2.f * L2E));
                const float tc = __builtin_fmaf(2.f, __builtin_amdgcn_rcpf(1.f + Ec), -1.f);
                const float h1v = go * tc;
                if (u < HID) HS[nxt][offA(mcol, u)] = (unsigned short)f2bf(h1v);
                float fcp = fcwv * h1v;
                fcp += __shfl_xor(fcp, 16);
                fcp += __shfl_xor(fcp, 32);
                if (lid < MB) FCP[tb & 1][w][lid] = fcp;
                if (lid == 0)                        // consumed slot tb (orders the reads)
                    __hip_atomic_fetch_add(bctr, 1u, __ATOMIC_RELEASE, __HIP_MEMORY_SCOPE_AGENT);
            } else if (w == NWC && lid < MB && tb >= 1) {
                float s = fcb;
                #pragma unroll
                for (int vv = 0; vv < NWC; ++vv) s += FCP[(tb - 1) & 1][vv][lid];
                out[(size_t)(tb - 1) * BATCH + b0 + lid] = s;
            }
            PHASE_BARRIER();
        }
        if (w == NWC && lid < MB) {                  // final step's FC
            float s = fcb;
            #pragma unroll
            for (int vv = 0; vv < NWC; ++vv) s += FCP[(T_STEPS - 1) & 1][vv][lid];
            out[(size_t)(T_STEPS - 1) * BATCH + b0 + lid] = s;
        }
    }
}

extern "C" void kernel_launch(void* const* d_in, const int* in_sizes, int n_in,
                              void* d_out, int out_size, void* d_ws, size_t ws_size,
                              hipStream_t stream) {
    const float* x     = (const float*)d_in[0];
    const float* w_ih0 = (const float*)d_in[1];
    const float* w_hh0 = (const float*)d_in[2];
    const float* b_ih0 = (const float*)d_in[3];
    const float* b_hh0 = (const float*)d_in[4];
    const float* w_ih1 = (const float*)d_in[5];
    const float* w_hh1 = (const float*)d_in[6];
    const float* b_ih1 = (const float*)d_in[7];
    const float* b_hh1 = (const float*)d_in[8];
    const float* fc_w  = (const float*)d_in[9];
    const float* fc_b  = (const float*)d_in[10];
    float* out = (float*)d_out;

    // zero handoff counters + ring slots every launch (stream-ordered,
    // graph-capture safe) so replays are deterministic.
    hipMemsetAsync(d_ws, 0, (size_t)WS_DW * 4, stream);

    lstm_ab<<<dim3(2 * NPAIR), dim3(NT), 0, stream>>>(
        x, w_ih0, w_hh0, b_ih0, b_hh0,
        w_ih1, w_hh1, b_ih1, b_hh1, fc_w, fc_b,
        out, (unsigned*)d_ws);
}

// Round 9
// 334.372 us; speedup vs baseline: 62.9199x; 62.9199x over previous
//
#include <hip/hip_runtime.h>

#define T_STEPS 365
#define BATCH   2048
#define INP     9
#define HID     50
#define MB      16          // batch per block (MFMA col dim)
#define NBLK    (BATCH/MB)  // 128
#define NT      896         // 14 waves: 0-12 merged L0+L1 tiles, 13 util
#define NWC     13          // compute waves (13 tiles of 16 gate rows)
#define L2E     1.4426950408889634f

typedef __attribute__((ext_vector_type(8))) short short8;
typedef __attribute__((ext_vector_type(4))) float float4v;

__device__ __forceinline__ unsigned f2bf(float v) {
    unsigned u = __builtin_bit_cast(unsigned, v);
    return (u + 0x7FFFu + ((u >> 16) & 1u)) >> 16;
}

// lgkm-only phase barrier: LDS drains, global loads stay in flight.
#define PHASE_BARRIER() do {                                  \
    asm volatile("s_waitcnt lgkmcnt(0)" ::: "memory");        \
    __builtin_amdgcn_s_barrier();                             \
    __builtin_amdgcn_sched_barrier(0);                        \
} while (0)

// HX[p]: [16 batch rows][128 bf16 cols]: 0-49 h0 | 50-58 x | 59-63 zero | 64-113 h1 | 114-127 zero
// XOR swizzle keeps b128 fragment reads 2-way max (free per m136).
__device__ __forceinline__ int hx_off(int m, int k) {   // ushort units
    return (m * 128 + k) ^ ((m & 7) << 3);
}

// Merged-role LSTM: wave T computes BOTH layer0-tile T (step ph) and
// layer1-tile T (step ph-1) each phase — two independent dependency chains
// per wave, interleaved by the compiler, so each chain's stalls are filled
// by the other's issue. One lgkm-only barrier per phase.
__global__ __launch_bounds__(NT, 3)
void lstm_merged(const float* __restrict__ x,
                 const float* __restrict__ w_ih0, const float* __restrict__ w_hh0,
                 const float* __restrict__ b_ih0, const float* __restrict__ b_hh0,
                 const float* __restrict__ w_ih1, const float* __restrict__ w_hh1,
                 const float* __restrict__ b_ih1, const float* __restrict__ b_hh1,
                 const float* __restrict__ fc_w, const float* __restrict__ fc_b,
                 float* __restrict__ out)
{
    __shared__ __align__(16) unsigned short HX[2][MB * 128];
    __shared__ float FCP[2][NWC][MB];

    const int tid  = threadIdx.x;
    const int w    = tid >> 6;
    const int lid  = tid & 63;
    const int mcol = lid & 15;
    const int kgrp = lid >> 4;
    const int kb8  = kgrp * 8;
    const int b0   = blockIdx.x * MB;
    const bool cw  = (w < NWC);
    const float fcb = fc_b[0];

    // ---- per-wave tile identity (gate-interleaved rows: r = 4*unit + gate
    //      -> original row = gate*50 + unit) ----
    const int T = cw ? w : 0;
    const int r = T * 16 + mcol;
    const bool rv = cw && (r < 4 * HID);
    const int u_r = r >> 2, g_r = r & 3;
    const int orig = g_r * HID + u_r;
    const float rsc = (g_r == 2) ? (-2.f * L2E) : (-L2E);   // exp2 prescale
    const int u = T * 4 + kgrp;              // unit this lane's D-regs cover

    // wk0: L0 [w_hh0 on h0(50) | w_ih0 on x(9) | 0]  (K=64, 2 halves)
    // wk1: L1 w_ih1 on h0(50)   (cols 50-63 zero -> x contamination killed)
    // wk2: L1 w_hh1 on h1(50)
    short8 wk0[2], wk1[2], wk2[2];
    #pragma unroll
    for (int q = 0; q < 2; ++q) {
        short8 a{}, b{}, c{};
        #pragma unroll
        for (int j = 0; j < 8; ++j) {
            const int k = q * 32 + kb8 + j;
            float v0 = 0.f, v1 = 0.f, v2 = 0.f;
            if (rv) {
                if (k < HID) {
                    v0 = w_hh0[orig * HID + k];
                    v1 = w_ih1[orig * HID + k];
                    v2 = w_hh1[orig * HID + k];
                } else if (k < HID + INP) {
                    v0 = w_ih0[orig * INP + (k - HID)];
                }
            }
            a[j] = (short)f2bf(v0 * rsc);
            b[j] = (short)f2bf(v1 * rsc);
            c[j] = (short)f2bf(v2 * rsc);
        }
        wk0[q] = a; wk1[q] = b; wk2[q] = c;
    }
    float bs0[4], bs1[4];
    #pragma unroll
    for (int rr = 0; rr < 4; ++rr) {
        const int row = T * 16 + kgrp * 4 + rr;   // = 4*u + rr
        const bool bv = cw && (row < 4 * HID);
        const float bsc = (rr == 2) ? (-2.f * L2E) : (-L2E);
        bs0[rr] = bv ? (b_ih0[rr * HID + u] + b_hh0[rr * HID + u]) * bsc : 0.f;
        bs1[rr] = bv ? (b_ih1[rr * HID + u] + b_hh1[rr * HID + u]) * bsc : 0.f;
    }
    const float fcwv = (cw && u < HID) ? fc_w[u] : 0.f;
    float cst0 = 0.f, cst1 = 0.f;

    // ---- util wave (w == NWC): lanes 0-47 load x (3 values each),
    //      lanes 48-63 write out ----
    const bool xact = (!cw) && (lid < 48);
    const bool oact = (!cw) && (lid >= 48);
    const int om = lid - 48;
    float xr[3] = {0.f, 0.f, 0.f};

    // ---- LDS init ----
    for (int i = tid; i < 2 * MB * 128; i += NT) (&HX[0][0])[i] = 0;
    for (int i = tid; i < 2 * NWC * MB; i += NT) (&FCP[0][0][0])[i] = 0.f;
    __syncthreads();
    if (xact) {
        #pragma unroll
        for (int q = 0; q < 3; ++q) {
            const int xi = lid * 3 + q;
            if (xi < MB * INP) {
                const int m = xi / INP, j = xi - m * INP;
                // x(0) into buf1 (phase 0 reads cur = 1); xr <- x(1)
                HX[1][hx_off(m, HID + j)] =
                    (unsigned short)f2bf(x[(size_t)(b0 + m) * INP + j]);
                xr[q] = x[((size_t)BATCH + b0 + m) * INP + j];
            }
        }
    }
    __syncthreads();

    for (int ph = 0; ph <= T_STEPS + 1; ++ph) {
        const int cur = (ph + 1) & 1, nxt = ph & 1;

        if (cw) {
            // shared fragment reads: f0/f1 feed BOTH chains (h0(ph-1)+x(ph));
            // f2/f3 feed the L1 chain (h1(ph-2)).
            const short8 f0 = *(const short8*)&HX[cur][hx_off(mcol, kb8)];
            const short8 f1 = *(const short8*)&HX[cur][hx_off(mcol, 32 + kb8)];
            const short8 f2 = *(const short8*)&HX[cur][hx_off(mcol, 64 + kb8)];
            const short8 f3 = *(const short8*)&HX[cur][hx_off(mcol, 96 + kb8)];

            // ---- chain A: layer0 step ph ----
            if (ph < T_STEPS) {
                float4v acc = {bs0[0], bs0[1], bs0[2], bs0[3]};
                acc = __builtin_amdgcn_mfma_f32_16x16x32_bf16(wk0[0], f0, acc, 0, 0, 0);
                acc = __builtin_amdgcn_mfma_f32_16x16x32_bf16(wk0[1], f1, acc, 0, 0, 0);
                const float gi = __builtin_amdgcn_rcpf(1.f + __builtin_amdgcn_exp2f(acc[0]));
                const float gf = __builtin_amdgcn_rcpf(1.f + __builtin_amdgcn_exp2f(acc[1]));
                const float g2 = __builtin_amdgcn_rcpf(1.f + __builtin_amdgcn_exp2f(acc[2]));
                const float go = __builtin_amdgcn_rcpf(1.f + __builtin_amdgcn_exp2f(acc[3]));
                const float gg = __builtin_fmaf(2.f, g2, -1.f);
                cst0 = gf * cst0 + gi * gg;
                const float Ec = __builtin_amdgcn_exp2f(cst0 * (-2.f * L2E));
                const float tc = __builtin_fmaf(2.f, __builtin_amdgcn_rcpf(1.f + Ec), -1.f);
                const float h0v = go * tc;
                if (u < HID) HX[nxt][hx_off(mcol, u)] = (unsigned short)f2bf(h0v);
            }

            // ---- chain B: layer1 step ph-1 (+ FC partial) ----
            if (ph >= 1 && ph <= T_STEPS) {
                float4v accA = {bs1[0], bs1[1], bs1[2], bs1[3]};
                float4v accB = {0.f, 0.f, 0.f, 0.f};
                accA = __builtin_amdgcn_mfma_f32_16x16x32_bf16(wk1[0], f0, accA, 0, 0, 0);
                accB = __builtin_amdgcn_mfma_f32_16x16x32_bf16(wk2[0], f2, accB, 0, 0, 0);
                accA = __builtin_amdgcn_mfma_f32_16x16x32_bf16(wk1[1], f1, accA, 0, 0, 0);
                accB = __builtin_amdgcn_mfma_f32_16x16x32_bf16(wk2[1], f3, accB, 0, 0, 0);
                const float gi = __builtin_amdgcn_rcpf(1.f + __builtin_amdgcn_exp2f(accA[0] + accB[0]));
                const float gf = __builtin_amdgcn_rcpf(1.f + __builtin_amdgcn_exp2f(accA[1] + accB[1]));
                const float g2 = __builtin_amdgcn_rcpf(1.f + __builtin_amdgcn_exp2f(accA[2] + accB[2]));
                const float go = __builtin_amdgcn_rcpf(1.f + __builtin_amdgcn_exp2f(accA[3] + accB[3]));
                const float gg = __builtin_fmaf(2.f, g2, -1.f);
                cst1 = gf * cst1 + gi * gg;
                const float Ec = __builtin_amdgcn_exp2f(cst1 * (-2.f * L2E));
                const float tc = __builtin_fmaf(2.f, __builtin_amdgcn_rcpf(1.f + Ec), -1.f);
                const float h1v = go * tc;
                if (u < HID) HX[nxt][hx_off(mcol, 64 + u)] = (unsigned short)f2bf(h1v);
                float fcp = fcwv * h1v;
                fcp += __shfl_xor(fcp, 16);
                fcp += __shfl_xor(fcp, 32);
                if (lid < MB) FCP[ph & 1][w][lid] = fcp;
            }
        } else if (xact) {
            // ---- x staging: write x(ph+1) (loaded 2 phases ago), load x(ph+2) ----
            #pragma unroll
            for (int q = 0; q < 3; ++q) {
                const int xi = lid * 3 + q;
                if (xi < MB * INP) {
                    const int m = xi / INP, j = xi - m * INP;
                    float xn = 0.f;
                    if (ph + 2 < T_STEPS)
                        xn = x[((size_t)(ph + 2) * BATCH + b0 + m) * INP + j];
                    if (ph + 1 < T_STEPS)
                        HX[nxt][hx_off(m, HID + j)] = (unsigned short)f2bf(xr[q]);
                    xr[q] = xn;
                }
            }
        } else if (oact && ph >= 2) {
            // ---- out writer: out[ph-2] from FCP written at phase ph-1 ----
            const int rp = (ph - 1) & 1;
            float s = fcb;
            #pragma unroll
            for (int vv = 0; vv < NWC; ++vv) s += FCP[rp][vv][om];
            out[(size_t)(ph - 2) * BATCH + b0 + om] = s;
        }
        PHASE_BARRIER();
    }
}

extern "C" void kernel_launch(void* const* d_in, const int* in_sizes, int n_in,
                              void* d_out, int out_size, void* d_ws, size_t ws_size,
                              hipStream_t stream) {
    const float* x     = (const float*)d_in[0];
    const float* w_ih0 = (const float*)d_in[1];
    const float* w_hh0 = (const float*)d_in[2];
    const float* b_ih0 = (const float*)d_in[3];
    const float* b_hh0 = (const float*)d_in[4];
    const float* w_ih1 = (const float*)d_in[5];
    const float* w_hh1 = (const float*)d_in[6];
    const float* b_ih1 = (const float*)d_in[7];
    const float* b_hh1 = (const float*)d_in[8];
    const float* fc_w  = (const float*)d_in[9];
    const float* fc_b  = (const float*)d_in[10];
    float* out = (float*)d_out;

    lstm_merged<<<dim3(NBLK), dim3(NT), 0, stream>>>(
        x, w_ih0, w_hh0, b_ih0, b_hh0,
        w_ih1, w_hh1, b_ih1, b_hh1, fc_w, fc_b, out);
}